// Round 18
// baseline (132.928 us; speedup 1.0000x reference)
//
#include <hip/hip_runtime.h>

#define CC 64      // channels
#define SS 16384   // D*W*H
#define NN 65536   // B*S tokens
#define KK 2048    // codebook size
#define BM 64      // tokens per block tile (conv/finish)
#define BMA 128    // tokens per argmin block

typedef __attribute__((ext_vector_type(8))) short bf16x8_t;
typedef __attribute__((ext_vector_type(4))) float fx4_t;
#define MFMA16 __builtin_amdgcn_mfma_f32_16x16x32_bf16

__device__ __forceinline__ unsigned short f2bf(float f) {
  unsigned u = __builtin_bit_cast(unsigned, f);
  return (unsigned short)((u + 0x7fff + ((u >> 16) & 1)) >> 16);  // RNE
}
__device__ __forceinline__ float bf2f(unsigned short h) {
  unsigned u = (unsigned)h << 16;
  return __builtin_bit_cast(float, u);
}
__device__ __forceinline__ void glds16(const void* g, void* l) {
  __builtin_amdgcn_global_load_lds(
      (const __attribute__((address_space(1))) unsigned*)g,
      (__attribute__((address_space(3))) unsigned*)l, 16, 0, 0);
}

// == kernel 1: pre = W_in @ x + b_in (fp64, 4x4 tile)  [+ codebook split] ==
// Blocks >= NN/BM run the former vq_split (8 blocks). Block 0 also zeroes
// the loss accumulator + done counter (replaces the hipMemsetAsync node;
// conv_in completes before finish launches -> ordering is stream-level).
__global__ __launch_bounds__(256, 4) void vq_conv_in(
    const float* __restrict__ x, const float* __restrict__ w_in,
    const float* __restrict__ b_in, float* __restrict__ xf,
    const float* __restrict__ cb, unsigned short* __restrict__ cbh,
    unsigned short* __restrict__ cbl, float* __restrict__ ch,
    float* __restrict__ loss_acc, unsigned* __restrict__ done_ct) {
  __shared__ float xs[CC][BM];
  __shared__ float wt[CC][CC];
  int t = threadIdx.x;
  if (blockIdx.x == 0 && t == 0) {  // re-zeroed every launch (replay-safe)
    loss_acc[0] = 0.0f;
    done_ct[0] = 0u;
  }
  if (blockIdx.x >= NN / BM) {  // ---- split path (8 blocks) ----
    int k = (blockIdx.x - NN / BM) * 256 + t;
    const float4* r = (const float4*)(cb + (size_t)k * CC);
    unsigned* oh = (unsigned*)(cbh + (size_t)k * CC);
    unsigned* ol = (unsigned*)(cbl + (size_t)k * CC);
    float s = 0.f;
#pragma unroll
    for (int i = 0; i < 16; ++i) {
      float4 v = r[i];
      float vv[4] = {v.x, v.y, v.z, v.w};
      unsigned short h[4], l[4];
#pragma unroll
      for (int u = 0; u < 4; ++u) {
        s = fmaf(vv[u], vv[u], s);
        h[u] = f2bf(vv[u]);
        l[u] = f2bf(vv[u] - bf2f(h[u]));
      }
      oh[2 * i + 0] = (unsigned)h[0] | ((unsigned)h[1] << 16);
      oh[2 * i + 1] = (unsigned)h[2] | ((unsigned)h[3] << 16);
      ol[2 * i + 0] = (unsigned)l[0] | ((unsigned)l[1] << 16);
      ol[2 * i + 1] = (unsigned)l[2] | ((unsigned)l[3] << 16);
    }
    ch[k] = -0.5f * s;
    return;
  }
  int n0 = blockIdx.x * BM;
  int b = n0 >> 14, s0 = n0 & (SS - 1);
  {
    int o = t >> 2, c0 = (t & 3) * 16;
    const float4* wr = (const float4*)(w_in + o * CC + c0);
#pragma unroll
    for (int i = 0; i < 4; ++i) {
      float4 v = wr[i];
      int ci = c0 + 4 * i;
      wt[ci + 0][o] = v.x; wt[ci + 1][o] = v.y;
      wt[ci + 2][o] = v.z; wt[ci + 3][o] = v.w;
    }
  }
#pragma unroll
  for (int i = 0; i < 4; ++i) {
    int e4 = t + 256 * i;
    int ci = e4 >> 4, tok4 = (e4 & 15) * 4;
    *(float4*)&xs[ci][tok4] =
        *(const float4*)(x + (size_t)b * CC * SS + (size_t)ci * SS + s0 + tok4);
  }
  __syncthreads();
  int tx = t & 15, ty = t >> 4;
  double acc[4][4];
#pragma unroll
  for (int j = 0; j < 4; ++j) {
    double bj = (double)b_in[tx * 4 + j];
#pragma unroll
    for (int m = 0; m < 4; ++m) acc[m][j] = bj;
  }
#pragma unroll 8
  for (int ci = 0; ci < CC; ++ci) {
    float4 xq = *(const float4*)&xs[ci][ty * 4];
    float4 wq = *(const float4*)&wt[ci][tx * 4];
    double xm[4] = {xq.x, xq.y, xq.z, xq.w};
    double wm[4] = {wq.x, wq.y, wq.z, wq.w};
#pragma unroll
    for (int m = 0; m < 4; ++m)
#pragma unroll
      for (int j = 0; j < 4; ++j) acc[m][j] = fma(xm[m], wm[j], acc[m][j]);
  }
#pragma unroll
  for (int j = 0; j < 4; ++j) {
    float4 ov = make_float4((float)acc[0][j], (float)acc[1][j],
                            (float)acc[2][j], (float)acc[3][j]);
    *(float4*)(xf + (size_t)b * CC * SS + (size_t)(tx * 4 + j) * SS + s0 +
               ty * 4) = ov;
  }
}

// ====== kernel 2: MFMA scan (R12 exact), best-only in-loop select ========
// blockIdx bit0 = K-half; 16 tiles of 64 codes, B dbuf via glds (inverse-
// swizzled source), cn staged in LDS. In-loop select = best-only per column
// (3 VALU/value); top-2 recovered at the 16-column merge; fp64 rerank in
// finish. [Proven config: R13 counted-vmcnt, R14 rt=4, R15 tail-fusion all
// regressed — allocator pins 64 VGPR; 2-phase schedule is the floor here.]
__global__ __launch_bounds__(256, 4) void vq_mfma_argmin(
    const float* __restrict__ xf, const unsigned char* __restrict__ cbh,
    const unsigned char* __restrict__ cbl, const float* __restrict__ ch,
    int* __restrict__ cidx) {
  __shared__ __align__(16) unsigned char smem[36864];  // 32K x/Bdbuf + 4K cn
  int t = threadIdx.x;
  int kh = blockIdx.x & 1;
  int n0 = (blockIdx.x >> 1) * BMA;
  int b = n0 >> 14, s0 = n0 & (SS - 1);
  int lane = t & 63, w = t >> 6;
  // stage this half's cn (4KB) into LDS [32768..36864) — overlaps phase A
  glds16((const unsigned char*)ch + kh * 4096 + w * 1024 + lane * 16,
         smem + 32768 + w * 1024);
  // ---- phase A: stage x as bf16 hi/lo token-major, swizzled ----
  {
    int tok = t & 127;
    int half = t >> 7;
    const float* xb = xf + (size_t)b * CC * SS + s0 + tok;
#pragma unroll
    for (int i = 0; i < 4; ++i) {
      int c0 = half * 32 + i * 8;
      bf16x8_t h8, l8;
#pragma unroll
      for (int j = 0; j < 8; ++j) {
        float v = xb[(size_t)(c0 + j) * SS];
        unsigned short hs = f2bf(v);
        h8[j] = (short)hs;
        l8[j] = (short)f2bf(v - bf2f(hs));
      }
      int ad = tok * 128 + ((half * 64 + i * 16) ^ ((tok & 7) << 4));
      *(bf16x8_t*)(smem + ad) = h8;
      *(bf16x8_t*)(smem + 16384 + ad) = l8;
    }
  }
  __syncthreads();
  int col = lane & 15, quad = lane >> 4;
  bf16x8_t ah[2][2], al[2][2];
#pragma unroll
  for (int rt = 0; rt < 2; ++rt)
#pragma unroll
    for (int kk = 0; kk < 2; ++kk) {
      int tok = w * 32 + rt * 16 + col;
      int ad = tok * 128 + ((kk * 64 + quad * 16) ^ ((tok & 7) << 4));
      ah[rt][kk] = *(const bf16x8_t*)(smem + ad);
      al[rt][kk] = *(const bf16x8_t*)(smem + 16384 + ad);
    }
  __syncthreads();  // x consumed; smem[0..32K) -> B double-buffer
  float best[2][4];
  int bi[2][4];
#pragma unroll
  for (int rt = 0; rt < 2; ++rt)
#pragma unroll
    for (int r = 0; r < 4; ++r) {
      best[rt][r] = -3.402823466e+38f;
      bi[rt][r] = 0;
    }
  int srcoff = (lane * 16) ^ (((lane >> 3) & 7) << 4);  // inverse swizzle
  const unsigned char* ghh = cbh + (size_t)kh * 131072;
  const unsigned char* glh = cbl + (size_t)kh * 131072;
  // prologue: B tile 0 (64 codes: hi 8KB + lo 8KB; wave w -> 2KB each)
  glds16(ghh + w * 2048 + srcoff, smem + w * 2048);
  glds16(ghh + w * 2048 + 1024 + srcoff, smem + w * 2048 + 1024);
  glds16(glh + w * 2048 + srcoff, smem + 8192 + w * 2048);
  glds16(glh + w * 2048 + 1024 + srcoff, smem + 8192 + w * 2048 + 1024);
  __syncthreads();
  int swz = (col & 7) << 4;
  int cbo0 = col * 128 + ((quad * 16) ^ swz);
  int cbo1 = col * 128 + ((64 + quad * 16) ^ swz);
  int kcol = kh * 1024 + col;
  const int NT = 16;
  for (int kt = 0; kt < NT; ++kt) {
    unsigned char* bufc = smem + (kt & 1) * 16384;
    unsigned char* bufn = smem + ((kt + 1) & 1) * 16384;
    if (kt + 1 < NT) {
      size_t gof = (size_t)(kt + 1) * 8192 + w * 2048 + srcoff;
      glds16(ghh + gof, bufn + w * 2048);
      glds16(ghh + gof + 1024, bufn + w * 2048 + 1024);
      glds16(glh + gof, bufn + 8192 + w * 2048);
      glds16(glh + gof + 1024, bufn + 8192 + w * 2048 + 1024);
    }
    const unsigned char* cnb = smem + 32768 + kt * 256 + col * 4;
    int kbt = kcol + kt * 64;
#pragma unroll
    for (int sub = 0; sub < 4; ++sub) {
      bf16x8_t bh0 = *(const bf16x8_t*)(bufc + cbo0 + 2048 * sub);
      bf16x8_t bh1 = *(const bf16x8_t*)(bufc + cbo1 + 2048 * sub);
      bf16x8_t bl0 = *(const bf16x8_t*)(bufc + 8192 + cbo0 + 2048 * sub);
      bf16x8_t bl1 = *(const bf16x8_t*)(bufc + 8192 + cbo1 + 2048 * sub);
      float cn = *(const float*)(cnb + 64 * sub);
      int kbase = kbt + sub * 16;
#pragma unroll
      for (int rt = 0; rt < 2; ++rt) {
        fx4_t acc = {cn, cn, cn, cn};
        acc = MFMA16(al[rt][0], bh0, acc, 0, 0, 0);  // lh
        acc = MFMA16(al[rt][1], bh1, acc, 0, 0, 0);
        acc = MFMA16(ah[rt][0], bl0, acc, 0, 0, 0);  // hl
        acc = MFMA16(ah[rt][1], bl1, acc, 0, 0, 0);
        acc = MFMA16(ah[rt][0], bh0, acc, 0, 0, 0);  // hh
        acc = MFMA16(ah[rt][1], bh1, acc, 0, 0, 0);
        // best-only select (3 VALU/value; ascending k + strict > ==
        // first-occurrence within the column)
#pragma unroll
        for (int r = 0; r < 4; ++r) {
          float v = acc[r];
          bool g = v > best[rt][r];
          best[rt][r] = g ? v : best[rt][r];
          bi[rt][r] = g ? kbase : bi[rt][r];
        }
      }
    }
    __syncthreads();
  }
  // 16-column merge with top-2 recovery (lex: max S, min k)
  float secd[2][4];
  int si[2][4];
#pragma unroll
  for (int rt = 0; rt < 2; ++rt)
#pragma unroll
    for (int r = 0; r < 4; ++r) {
      secd[rt][r] = -3.402823466e+38f;
      si[rt][r] = 0x7fffffff;
    }
#pragma unroll
  for (int step = 1; step <= 8; step <<= 1) {
#pragma unroll
    for (int rt = 0; rt < 2; ++rt)
#pragma unroll
      for (int r = 0; r < 4; ++r) {
        float ob = __shfl_xor(best[rt][r], step, 64);
        int oi = __shfl_xor(bi[rt][r], step, 64);
        float os = __shfl_xor(secd[rt][r], step, 64);
        int oj = __shfl_xor(si[rt][r], step, 64);
        bool oW = (ob > best[rt][r]) || (ob == best[rt][r] && oi < bi[rt][r]);
        float nb = oW ? ob : best[rt][r];
        int ni = oW ? oi : bi[rt][r];
        float lb = oW ? best[rt][r] : ob;
        int li = oW ? bi[rt][r] : oi;
        float ws = oW ? os : secd[rt][r];
        int wi = oW ? oj : si[rt][r];
        bool sW = (ws > lb) || (ws == lb && wi < li);
        best[rt][r] = nb; bi[rt][r] = ni;
        secd[rt][r] = sW ? ws : lb; si[rt][r] = sW ? wi : li;
      }
  }
  if (col == 0) {
#pragma unroll
    for (int rt = 0; rt < 2; ++rt)
#pragma unroll
      for (int r = 0; r < 4; ++r) {
        int token = n0 + w * 32 + rt * 16 + quad * 4 + r;
        cidx[(size_t)(2 * kh + 0) * NN + token] = bi[rt][r];
        cidx[(size_t)(2 * kh + 1) * NN + token] = si[rt][r];
      }
  }
}

// == kernel 3: fused fp64 select + gather q + losses + conv_out + finalize =
// Body identical to R17 (proven). Tail: done-counter finalize — last block
// reads the L2-coherent loss total and writes the two scalars (removes the
// 1-thread vq_finalize dispatch). R15's regression was the select-rewrite
// spill, not this pattern; body registers untouched here.
__global__ __launch_bounds__(256, 4) void vq_finish(
    const float* __restrict__ cb, const float* __restrict__ w_out,
    const float* __restrict__ b_out, const int* __restrict__ cidx,
    float* __restrict__ dout, float* __restrict__ loss_acc,
    unsigned* __restrict__ done_ct) {
  __shared__ float qs[CC][BM];
  __shared__ float sbuf[CC][BM];  // xs (early) / wt (late)
  int t = threadIdx.x;
  int n0 = blockIdx.x * BM;
  int b = n0 >> 14, s0 = n0 & (SS - 1);
  float* zreg = dout + (size_t)NN * CC;
#pragma unroll
  for (int i = 0; i < 4; ++i) {  // stage xs (= xf) from z region
    int e4 = t + 256 * i;
    int ci = e4 >> 4, tok4 = (e4 & 15) * 4;
    *(float4*)&sbuf[ci][tok4] = *(const float4*)(zreg + (size_t)b * CC * SS +
                                                 (size_t)ci * SS + s0 + tok4);
  }
  __syncthreads();
  int tok = t >> 2, cand = t & 3;
  int kj;
  {  // fused exact fp64 selection: 4 threads per token, lex-min (d, k);
    // butterfly leaves the winner in ALL 4 lanes -> no ids[] / no barrier
    kj = cidx[(size_t)cand * NN + n0 + tok];
    const float* cp = cb + (size_t)kj * CC;
    double dj = 0.0;
#pragma unroll 8
    for (int c = 0; c < CC; ++c) {
      double df = (double)sbuf[c][tok] - (double)cp[c];
      dj = fma(df, df, dj);
    }
#pragma unroll
    for (int step = 1; step <= 2; step <<= 1) {
      double od = __shfl_xor(dj, step, 64);
      int ok = __shfl_xor(kj, step, 64);
      if (od < dj || (od == dj && ok < kj)) { dj = od; kj = ok; }
    }
  }
  {  // stage qs[ch][tok] = codebook[kj] (each of the 4 lanes: 16 channels)
    int c0 = cand * 16;
    const float4* qr = (const float4*)(cb + (size_t)kj * CC + c0);
#pragma unroll
    for (int i = 0; i < 4; ++i) {
      float4 v = qr[i];
      int ch = c0 + 4 * i;
      qs[ch + 0][tok] = v.x; qs[ch + 1][tok] = v.y;
      qs[ch + 2][tok] = v.z; qs[ch + 3][tok] = v.w;
    }
  }
  __syncthreads();
  float lsum = 0.f;
#pragma unroll
  for (int i = 0; i < 4; ++i) {  // losses + z := q (reads sbuf=xs, qs)
    int e4 = t + 256 * i;
    int ci = e4 >> 4, tok4 = (e4 & 15) * 4;
    float4 qv = *(const float4*)&qs[ci][tok4];
    float4 xv = *(const float4*)&sbuf[ci][tok4];
    float dx = qv.x - xv.x, dy = qv.y - xv.y;
    float dz = qv.z - xv.z, dw = qv.w - xv.w;
    lsum = fmaf(dx, dx, lsum); lsum = fmaf(dy, dy, lsum);
    lsum = fmaf(dz, dz, lsum); lsum = fmaf(dw, dw, lsum);
    *(float4*)(zreg + (size_t)b * CC * SS + (size_t)ci * SS + s0 + tok4) = qv;
  }
  __syncthreads();  // xs fully consumed; sbuf becomes wt
  {  // stage wt transposed into sbuf: sbuf[ci][o] = w_out[o][ci]
    int o = t >> 2, c0 = (t & 3) * 16;
    const float4* wr = (const float4*)(w_out + o * CC + c0);
#pragma unroll
    for (int i = 0; i < 4; ++i) {
      float4 v = wr[i];
      int ci = c0 + 4 * i;
      sbuf[ci + 0][o] = v.x; sbuf[ci + 1][o] = v.y;
      sbuf[ci + 2][o] = v.z; sbuf[ci + 3][o] = v.w;
    }
  }
  __syncthreads();
  int tx = t & 15, ty = t >> 4;
  float acc[4][4];
#pragma unroll
  for (int j = 0; j < 4; ++j) {
    float bj = b_out[tx * 4 + j];
#pragma unroll
    for (int m = 0; m < 4; ++m) acc[m][j] = bj;
  }
#pragma unroll 8
  for (int ci = 0; ci < CC; ++ci) {
    float4 xq = *(const float4*)&qs[ci][ty * 4];
    float4 wq = *(const float4*)&sbuf[ci][tx * 4];
    float xm[4] = {xq.x, xq.y, xq.z, xq.w};
    float wm[4] = {wq.x, wq.y, wq.z, wq.w};
#pragma unroll
    for (int m = 0; m < 4; ++m)
#pragma unroll
      for (int j = 0; j < 4; ++j) acc[m][j] = fmaf(xm[m], wm[j], acc[m][j]);
  }
#pragma unroll
  for (int j = 0; j < 4; ++j) {
    float4 ov = make_float4(acc[0][j], acc[1][j], acc[2][j], acc[3][j]);
    *(float4*)(dout + (size_t)b * CC * SS + (size_t)(tx * 4 + j) * SS + s0 +
               ty * 4) = ov;
  }
#pragma unroll
  for (int off = 32; off > 0; off >>= 1) lsum += __shfl_down(lsum, off, 64);
  __shared__ float wsum[4];
  if ((t & 63) == 0) wsum[t >> 6] = lsum;
  __syncthreads();
  if (t == 0) {
    atomicAdd(loss_acc, wsum[0] + wsum[1] + wsum[2] + wsum[3]);
    __threadfence();  // loss add visible before counter bump
    unsigned old = atomicAdd(done_ct, 1u);
    if (old == (NN / BM) - 1) {  // last block: finalize scalars
      float l = atomicAdd(loss_acc, 0.0f) *  // L2-coherent read
                (1.0f / (float)((size_t)NN * CC));
      dout[(size_t)2 * NN * CC + 0] = l;  // codebook_loss
      dout[(size_t)2 * NN * CC + 1] = l;  // commitment_loss
    }
  }
}

extern "C" void kernel_launch(void* const* d_in, const int* in_sizes, int n_in,
                              void* d_out, int out_size, void* d_ws,
                              size_t ws_size, hipStream_t stream) {
  const float* x = (const float*)d_in[0];
  const float* cb = (const float*)d_in[1];
  const float* w_in = (const float*)d_in[2];
  const float* b_in = (const float*)d_in[3];
  const float* w_out = (const float*)d_in[4];
  const float* b_out = (const float*)d_in[5];
  float* out = (float*)d_out;
  float* zreg = out + (size_t)NN * CC;  // z region doubles as xf scratch

  // ws: [0,4) loss; [4,8) done counter; [1024,9216) ch; [16K,272K) cbh;
  //     [272K,528K) cbl; [528K,1552K) cidx (4 planes x NN). ~1.6 MB total.
  float* loss_acc = (float*)d_ws;
  unsigned* done_ct = (unsigned*)((char*)d_ws + 4);
  float* ch = (float*)((char*)d_ws + 1024);
  unsigned short* cbh = (unsigned short*)((char*)d_ws + 16384);
  unsigned short* cbl = (unsigned short*)((char*)d_ws + 16384 + 262144);
  int* cidx = (int*)((char*)d_ws + 16384 + 2 * 262144);

  vq_conv_in<<<NN / BM + KK / 256, 256, 0, stream>>>(
      x, w_in, b_in, zreg, cb, cbh, cbl, ch, loss_acc, done_ct);
  vq_mfma_argmin<<<(NN / BMA) * 2, 256, 0, stream>>>(
      zreg, (const unsigned char*)cbh, (const unsigned char*)cbl, ch, cidx);
  vq_finish<<<NN / BM, 256, 0, stream>>>(cb, w_out, b_out, cidx, out,
                                         loss_acc, done_ct);
}

// Round 19
// 102.658 us; speedup vs baseline: 1.2949x; 1.2949x over previous
//
#include <hip/hip_runtime.h>

#define CC 64      // channels
#define SS 16384   // D*W*H
#define NN 65536   // B*S tokens
#define KK 2048    // codebook size
#define BM 64      // tokens per block tile (conv/finish)
#define BMA 128    // tokens per argmin block

typedef __attribute__((ext_vector_type(8))) short bf16x8_t;
typedef __attribute__((ext_vector_type(4))) float fx4_t;
#define MFMA16 __builtin_amdgcn_mfma_f32_16x16x32_bf16

__device__ __forceinline__ unsigned short f2bf(float f) {
  unsigned u = __builtin_bit_cast(unsigned, f);
  return (unsigned short)((u + 0x7fff + ((u >> 16) & 1)) >> 16);  // RNE
}
__device__ __forceinline__ float bf2f(unsigned short h) {
  unsigned u = (unsigned)h << 16;
  return __builtin_bit_cast(float, u);
}
__device__ __forceinline__ void glds16(const void* g, void* l) {
  __builtin_amdgcn_global_load_lds(
      (const __attribute__((address_space(1))) unsigned*)g,
      (__attribute__((address_space(3))) unsigned*)l, 16, 0, 0);
}

// == kernel 1: pre = W_in @ x + b_in (fp64, 4x4 tile)  [+ codebook split] ==
// Blocks >= NN/BM run the former vq_split (8 blocks). Block 0 also zeroes
// the loss accumulator (replaces the hipMemsetAsync node; kernel-boundary
// visibility on the same stream covers the later atomicAdd readers).
// [R18 lesson: per-block __threadfence finalize costs ~33us — keep the
// 1-thread vq_finalize dispatch instead.]
__global__ __launch_bounds__(256, 4) void vq_conv_in(
    const float* __restrict__ x, const float* __restrict__ w_in,
    const float* __restrict__ b_in, float* __restrict__ xf,
    const float* __restrict__ cb, unsigned short* __restrict__ cbh,
    unsigned short* __restrict__ cbl, float* __restrict__ ch,
    float* __restrict__ loss_acc) {
  __shared__ float xs[CC][BM];
  __shared__ float wt[CC][CC];
  int t = threadIdx.x;
  if (blockIdx.x == 0 && t == 0) loss_acc[0] = 0.0f;  // replay-safe re-zero
  if (blockIdx.x >= NN / BM) {  // ---- split path (8 blocks) ----
    int k = (blockIdx.x - NN / BM) * 256 + t;
    const float4* r = (const float4*)(cb + (size_t)k * CC);
    unsigned* oh = (unsigned*)(cbh + (size_t)k * CC);
    unsigned* ol = (unsigned*)(cbl + (size_t)k * CC);
    float s = 0.f;
#pragma unroll
    for (int i = 0; i < 16; ++i) {
      float4 v = r[i];
      float vv[4] = {v.x, v.y, v.z, v.w};
      unsigned short h[4], l[4];
#pragma unroll
      for (int u = 0; u < 4; ++u) {
        s = fmaf(vv[u], vv[u], s);
        h[u] = f2bf(vv[u]);
        l[u] = f2bf(vv[u] - bf2f(h[u]));
      }
      oh[2 * i + 0] = (unsigned)h[0] | ((unsigned)h[1] << 16);
      oh[2 * i + 1] = (unsigned)h[2] | ((unsigned)h[3] << 16);
      ol[2 * i + 0] = (unsigned)l[0] | ((unsigned)l[1] << 16);
      ol[2 * i + 1] = (unsigned)l[2] | ((unsigned)l[3] << 16);
    }
    ch[k] = -0.5f * s;
    return;
  }
  int n0 = blockIdx.x * BM;
  int b = n0 >> 14, s0 = n0 & (SS - 1);
  {
    int o = t >> 2, c0 = (t & 3) * 16;
    const float4* wr = (const float4*)(w_in + o * CC + c0);
#pragma unroll
    for (int i = 0; i < 4; ++i) {
      float4 v = wr[i];
      int ci = c0 + 4 * i;
      wt[ci + 0][o] = v.x; wt[ci + 1][o] = v.y;
      wt[ci + 2][o] = v.z; wt[ci + 3][o] = v.w;
    }
  }
#pragma unroll
  for (int i = 0; i < 4; ++i) {
    int e4 = t + 256 * i;
    int ci = e4 >> 4, tok4 = (e4 & 15) * 4;
    *(float4*)&xs[ci][tok4] =
        *(const float4*)(x + (size_t)b * CC * SS + (size_t)ci * SS + s0 + tok4);
  }
  __syncthreads();
  int tx = t & 15, ty = t >> 4;
  double acc[4][4];
#pragma unroll
  for (int j = 0; j < 4; ++j) {
    double bj = (double)b_in[tx * 4 + j];
#pragma unroll
    for (int m = 0; m < 4; ++m) acc[m][j] = bj;
  }
#pragma unroll 8
  for (int ci = 0; ci < CC; ++ci) {
    float4 xq = *(const float4*)&xs[ci][ty * 4];
    float4 wq = *(const float4*)&wt[ci][tx * 4];
    double xm[4] = {xq.x, xq.y, xq.z, xq.w};
    double wm[4] = {wq.x, wq.y, wq.z, wq.w};
#pragma unroll
    for (int m = 0; m < 4; ++m)
#pragma unroll
      for (int j = 0; j < 4; ++j) acc[m][j] = fma(xm[m], wm[j], acc[m][j]);
  }
#pragma unroll
  for (int j = 0; j < 4; ++j) {
    float4 ov = make_float4((float)acc[0][j], (float)acc[1][j],
                            (float)acc[2][j], (float)acc[3][j]);
    *(float4*)(xf + (size_t)b * CC * SS + (size_t)(tx * 4 + j) * SS + s0 +
               ty * 4) = ov;
  }
}

// ====== kernel 2: MFMA scan (R12 exact), best-only in-loop select ========
// blockIdx bit0 = K-half; 16 tiles of 64 codes, B dbuf via glds (inverse-
// swizzled source), cn staged in LDS. In-loop select = best-only per column
// (3 VALU/value); top-2 recovered at the 16-column merge; fp64 rerank in
// finish. [Proven config: R13 counted-vmcnt, R14 rt=4, R15/R18 tail-fusion
// all regressed — allocator pins 64 VGPR; 2-phase schedule is the floor.]
__global__ __launch_bounds__(256, 4) void vq_mfma_argmin(
    const float* __restrict__ xf, const unsigned char* __restrict__ cbh,
    const unsigned char* __restrict__ cbl, const float* __restrict__ ch,
    int* __restrict__ cidx) {
  __shared__ __align__(16) unsigned char smem[36864];  // 32K x/Bdbuf + 4K cn
  int t = threadIdx.x;
  int kh = blockIdx.x & 1;
  int n0 = (blockIdx.x >> 1) * BMA;
  int b = n0 >> 14, s0 = n0 & (SS - 1);
  int lane = t & 63, w = t >> 6;
  // stage this half's cn (4KB) into LDS [32768..36864) — overlaps phase A
  glds16((const unsigned char*)ch + kh * 4096 + w * 1024 + lane * 16,
         smem + 32768 + w * 1024);
  // ---- phase A: stage x as bf16 hi/lo token-major, swizzled ----
  {
    int tok = t & 127;
    int half = t >> 7;
    const float* xb = xf + (size_t)b * CC * SS + s0 + tok;
#pragma unroll
    for (int i = 0; i < 4; ++i) {
      int c0 = half * 32 + i * 8;
      bf16x8_t h8, l8;
#pragma unroll
      for (int j = 0; j < 8; ++j) {
        float v = xb[(size_t)(c0 + j) * SS];
        unsigned short hs = f2bf(v);
        h8[j] = (short)hs;
        l8[j] = (short)f2bf(v - bf2f(hs));
      }
      int ad = tok * 128 + ((half * 64 + i * 16) ^ ((tok & 7) << 4));
      *(bf16x8_t*)(smem + ad) = h8;
      *(bf16x8_t*)(smem + 16384 + ad) = l8;
    }
  }
  __syncthreads();
  int col = lane & 15, quad = lane >> 4;
  bf16x8_t ah[2][2], al[2][2];
#pragma unroll
  for (int rt = 0; rt < 2; ++rt)
#pragma unroll
    for (int kk = 0; kk < 2; ++kk) {
      int tok = w * 32 + rt * 16 + col;
      int ad = tok * 128 + ((kk * 64 + quad * 16) ^ ((tok & 7) << 4));
      ah[rt][kk] = *(const bf16x8_t*)(smem + ad);
      al[rt][kk] = *(const bf16x8_t*)(smem + 16384 + ad);
    }
  __syncthreads();  // x consumed; smem[0..32K) -> B double-buffer
  float best[2][4];
  int bi[2][4];
#pragma unroll
  for (int rt = 0; rt < 2; ++rt)
#pragma unroll
    for (int r = 0; r < 4; ++r) {
      best[rt][r] = -3.402823466e+38f;
      bi[rt][r] = 0;
    }
  int srcoff = (lane * 16) ^ (((lane >> 3) & 7) << 4);  // inverse swizzle
  const unsigned char* ghh = cbh + (size_t)kh * 131072;
  const unsigned char* glh = cbl + (size_t)kh * 131072;
  // prologue: B tile 0 (64 codes: hi 8KB + lo 8KB; wave w -> 2KB each)
  glds16(ghh + w * 2048 + srcoff, smem + w * 2048);
  glds16(ghh + w * 2048 + 1024 + srcoff, smem + w * 2048 + 1024);
  glds16(glh + w * 2048 + srcoff, smem + 8192 + w * 2048);
  glds16(glh + w * 2048 + 1024 + srcoff, smem + 8192 + w * 2048 + 1024);
  __syncthreads();
  int swz = (col & 7) << 4;
  int cbo0 = col * 128 + ((quad * 16) ^ swz);
  int cbo1 = col * 128 + ((64 + quad * 16) ^ swz);
  int kcol = kh * 1024 + col;
  const int NT = 16;
  for (int kt = 0; kt < NT; ++kt) {
    unsigned char* bufc = smem + (kt & 1) * 16384;
    unsigned char* bufn = smem + ((kt + 1) & 1) * 16384;
    if (kt + 1 < NT) {
      size_t gof = (size_t)(kt + 1) * 8192 + w * 2048 + srcoff;
      glds16(ghh + gof, bufn + w * 2048);
      glds16(ghh + gof + 1024, bufn + w * 2048 + 1024);
      glds16(glh + gof, bufn + 8192 + w * 2048);
      glds16(glh + gof + 1024, bufn + 8192 + w * 2048 + 1024);
    }
    const unsigned char* cnb = smem + 32768 + kt * 256 + col * 4;
    int kbt = kcol + kt * 64;
#pragma unroll
    for (int sub = 0; sub < 4; ++sub) {
      bf16x8_t bh0 = *(const bf16x8_t*)(bufc + cbo0 + 2048 * sub);
      bf16x8_t bh1 = *(const bf16x8_t*)(bufc + cbo1 + 2048 * sub);
      bf16x8_t bl0 = *(const bf16x8_t*)(bufc + 8192 + cbo0 + 2048 * sub);
      bf16x8_t bl1 = *(const bf16x8_t*)(bufc + 8192 + cbo1 + 2048 * sub);
      float cn = *(const float*)(cnb + 64 * sub);
      int kbase = kbt + sub * 16;
#pragma unroll
      for (int rt = 0; rt < 2; ++rt) {
        fx4_t acc = {cn, cn, cn, cn};
        acc = MFMA16(al[rt][0], bh0, acc, 0, 0, 0);  // lh
        acc = MFMA16(al[rt][1], bh1, acc, 0, 0, 0);
        acc = MFMA16(ah[rt][0], bl0, acc, 0, 0, 0);  // hl
        acc = MFMA16(ah[rt][1], bl1, acc, 0, 0, 0);
        acc = MFMA16(ah[rt][0], bh0, acc, 0, 0, 0);  // hh
        acc = MFMA16(ah[rt][1], bh1, acc, 0, 0, 0);
        // best-only select (3 VALU/value; ascending k + strict > ==
        // first-occurrence within the column)
#pragma unroll
        for (int r = 0; r < 4; ++r) {
          float v = acc[r];
          bool g = v > best[rt][r];
          best[rt][r] = g ? v : best[rt][r];
          bi[rt][r] = g ? kbase : bi[rt][r];
        }
      }
    }
    __syncthreads();
  }
  // 16-column merge with top-2 recovery (lex: max S, min k)
  float secd[2][4];
  int si[2][4];
#pragma unroll
  for (int rt = 0; rt < 2; ++rt)
#pragma unroll
    for (int r = 0; r < 4; ++r) {
      secd[rt][r] = -3.402823466e+38f;
      si[rt][r] = 0x7fffffff;
    }
#pragma unroll
  for (int step = 1; step <= 8; step <<= 1) {
#pragma unroll
    for (int rt = 0; rt < 2; ++rt)
#pragma unroll
      for (int r = 0; r < 4; ++r) {
        float ob = __shfl_xor(best[rt][r], step, 64);
        int oi = __shfl_xor(bi[rt][r], step, 64);
        float os = __shfl_xor(secd[rt][r], step, 64);
        int oj = __shfl_xor(si[rt][r], step, 64);
        bool oW = (ob > best[rt][r]) || (ob == best[rt][r] && oi < bi[rt][r]);
        float nb = oW ? ob : best[rt][r];
        int ni = oW ? oi : bi[rt][r];
        float lb = oW ? best[rt][r] : ob;
        int li = oW ? bi[rt][r] : oi;
        float ws = oW ? os : secd[rt][r];
        int wi = oW ? oj : si[rt][r];
        bool sW = (ws > lb) || (ws == lb && wi < li);
        best[rt][r] = nb; bi[rt][r] = ni;
        secd[rt][r] = sW ? ws : lb; si[rt][r] = sW ? wi : li;
      }
  }
  if (col == 0) {
#pragma unroll
    for (int rt = 0; rt < 2; ++rt)
#pragma unroll
      for (int r = 0; r < 4; ++r) {
        int token = n0 + w * 32 + rt * 16 + quad * 4 + r;
        cidx[(size_t)(2 * kh + 0) * NN + token] = bi[rt][r];
        cidx[(size_t)(2 * kh + 1) * NN + token] = si[rt][r];
      }
  }
}

// == kernel 3: fused fp64 select (4 cands) + gather q + losses + conv_out ==
// R17-exact (proven): no ids[] (butterfly leaves winner in all 4 lanes),
// xs/wt time-share one 16KB buffer -> 32.3KB LDS, 4 blocks/CU. No fence.
__global__ __launch_bounds__(256, 4) void vq_finish(
    const float* __restrict__ cb, const float* __restrict__ w_out,
    const float* __restrict__ b_out, const int* __restrict__ cidx,
    float* __restrict__ dout, float* __restrict__ loss_acc) {
  __shared__ float qs[CC][BM];
  __shared__ float sbuf[CC][BM];  // xs (early) / wt (late)
  int t = threadIdx.x;
  int n0 = blockIdx.x * BM;
  int b = n0 >> 14, s0 = n0 & (SS - 1);
  float* zreg = dout + (size_t)NN * CC;
#pragma unroll
  for (int i = 0; i < 4; ++i) {  // stage xs (= xf) from z region
    int e4 = t + 256 * i;
    int ci = e4 >> 4, tok4 = (e4 & 15) * 4;
    *(float4*)&sbuf[ci][tok4] = *(const float4*)(zreg + (size_t)b * CC * SS +
                                                 (size_t)ci * SS + s0 + tok4);
  }
  __syncthreads();
  int tok = t >> 2, cand = t & 3;
  int kj;
  {  // fused exact fp64 selection: 4 threads per token, lex-min (d, k);
    // butterfly leaves the winner in ALL 4 lanes -> no ids[] / no barrier
    kj = cidx[(size_t)cand * NN + n0 + tok];
    const float* cp = cb + (size_t)kj * CC;
    double dj = 0.0;
#pragma unroll 8
    for (int c = 0; c < CC; ++c) {
      double df = (double)sbuf[c][tok] - (double)cp[c];
      dj = fma(df, df, dj);
    }
#pragma unroll
    for (int step = 1; step <= 2; step <<= 1) {
      double od = __shfl_xor(dj, step, 64);
      int ok = __shfl_xor(kj, step, 64);
      if (od < dj || (od == dj && ok < kj)) { dj = od; kj = ok; }
    }
  }
  {  // stage qs[ch][tok] = codebook[kj] (each of the 4 lanes: 16 channels)
    int c0 = cand * 16;
    const float4* qr = (const float4*)(cb + (size_t)kj * CC + c0);
#pragma unroll
    for (int i = 0; i < 4; ++i) {
      float4 v = qr[i];
      int ch = c0 + 4 * i;
      qs[ch + 0][tok] = v.x; qs[ch + 1][tok] = v.y;
      qs[ch + 2][tok] = v.z; qs[ch + 3][tok] = v.w;
    }
  }
  __syncthreads();
  float lsum = 0.f;
#pragma unroll
  for (int i = 0; i < 4; ++i) {  // losses + z := q (reads sbuf=xs, qs)
    int e4 = t + 256 * i;
    int ci = e4 >> 4, tok4 = (e4 & 15) * 4;
    float4 qv = *(const float4*)&qs[ci][tok4];
    float4 xv = *(const float4*)&sbuf[ci][tok4];
    float dx = qv.x - xv.x, dy = qv.y - xv.y;
    float dz = qv.z - xv.z, dw = qv.w - xv.w;
    lsum = fmaf(dx, dx, lsum); lsum = fmaf(dy, dy, lsum);
    lsum = fmaf(dz, dz, lsum); lsum = fmaf(dw, dw, lsum);
    *(float4*)(zreg + (size_t)b * CC * SS + (size_t)ci * SS + s0 + tok4) = qv;
  }
  __syncthreads();  // xs fully consumed; sbuf becomes wt
  {  // stage wt transposed into sbuf: sbuf[ci][o] = w_out[o][ci]
    int o = t >> 2, c0 = (t & 3) * 16;
    const float4* wr = (const float4*)(w_out + o * CC + c0);
#pragma unroll
    for (int i = 0; i < 4; ++i) {
      float4 v = wr[i];
      int ci = c0 + 4 * i;
      sbuf[ci + 0][o] = v.x; sbuf[ci + 1][o] = v.y;
      sbuf[ci + 2][o] = v.z; sbuf[ci + 3][o] = v.w;
    }
  }
  __syncthreads();
  int tx = t & 15, ty = t >> 4;
  float acc[4][4];
#pragma unroll
  for (int j = 0; j < 4; ++j) {
    float bj = b_out[tx * 4 + j];
#pragma unroll
    for (int m = 0; m < 4; ++m) acc[m][j] = bj;
  }
#pragma unroll 8
  for (int ci = 0; ci < CC; ++ci) {
    float4 xq = *(const float4*)&qs[ci][ty * 4];
    float4 wq = *(const float4*)&sbuf[ci][tx * 4];
    float xm[4] = {xq.x, xq.y, xq.z, xq.w};
    float wm[4] = {wq.x, wq.y, wq.z, wq.w};
#pragma unroll
    for (int m = 0; m < 4; ++m)
#pragma unroll
      for (int j = 0; j < 4; ++j) acc[m][j] = fmaf(xm[m], wm[j], acc[m][j]);
  }
#pragma unroll
  for (int j = 0; j < 4; ++j) {
    float4 ov = make_float4(acc[0][j], acc[1][j], acc[2][j], acc[3][j]);
    *(float4*)(dout + (size_t)b * CC * SS + (size_t)(tx * 4 + j) * SS + s0 +
               ty * 4) = ov;
  }
#pragma unroll
  for (int off = 32; off > 0; off >>= 1) lsum += __shfl_down(lsum, off, 64);
  __shared__ float wsum[4];
  if ((t & 63) == 0) wsum[t >> 6] = lsum;
  __syncthreads();
  if (t == 0) atomicAdd(loss_acc, wsum[0] + wsum[1] + wsum[2] + wsum[3]);
}

// ============ kernel 4: finalize scalar losses ============
__global__ void vq_finalize(const float* __restrict__ loss_acc,
                            float* __restrict__ dout) {
  float l = loss_acc[0] * (1.0f / (float)((size_t)NN * CC));
  dout[(size_t)2 * NN * CC + 0] = l;  // codebook_loss
  dout[(size_t)2 * NN * CC + 1] = l;  // commitment_loss
}

extern "C" void kernel_launch(void* const* d_in, const int* in_sizes, int n_in,
                              void* d_out, int out_size, void* d_ws,
                              size_t ws_size, hipStream_t stream) {
  const float* x = (const float*)d_in[0];
  const float* cb = (const float*)d_in[1];
  const float* w_in = (const float*)d_in[2];
  const float* b_in = (const float*)d_in[3];
  const float* w_out = (const float*)d_in[4];
  const float* b_out = (const float*)d_in[5];
  float* out = (float*)d_out;
  float* zreg = out + (size_t)NN * CC;  // z region doubles as xf scratch

  // ws: [0,4) loss; [1024,9216) ch; [16K,272K) cbh; [272K,528K) cbl;
  //     [528K,1552K) cidx (4 planes x NN). ~1.6 MB total.
  float* loss_acc = (float*)d_ws;
  float* ch = (float*)((char*)d_ws + 1024);
  unsigned short* cbh = (unsigned short*)((char*)d_ws + 16384);
  unsigned short* cbl = (unsigned short*)((char*)d_ws + 16384 + 262144);
  int* cidx = (int*)((char*)d_ws + 16384 + 2 * 262144);

  vq_conv_in<<<NN / BM + KK / 256, 256, 0, stream>>>(x, w_in, b_in, zreg, cb,
                                                     cbh, cbl, ch, loss_acc);
  vq_mfma_argmin<<<(NN / BMA) * 2, 256, 0, stream>>>(
      zreg, (const unsigned char*)cbh, (const unsigned char*)cbl, ch, cidx);
  vq_finish<<<NN / BM, 256, 0, stream>>>(cb, w_out, b_out, cidx, out,
                                         loss_acc);
  vq_finalize<<<1, 1, 0, stream>>>(loss_acc, out);
}